// Round 20
// baseline (134.202 us; speedup 1.0000x reference)
//
#include <hip/hip_runtime.h>
#include <hip/hip_fp16.h>
#include <math.h>

#define N_NODES 100000
#define N_EDGES 1600000
#define EMBED 64
#define HEADS 4
#define HDIM 16

// Padded CSR: 64 slots per node (degree is Poisson(16); max over 100K nodes < 50)
#define SLOTS 64

// Two-phase bucket partition (no global returning atomics on the hot path):
#define BKT_SHIFT 8
#define BKT_NODES 256                         // receivers per bucket
#define NBKT 391                              // ceil(100000/256)
#define BKT_CAP 5120                          // mean 4096 + 16 sigma
#define TILE 4096                             // edges per bucketa-role block
#define NTILE 391                             // ceil(1600000/4096)
#define NGRP (N_EDGES / 4)                    // 400000 int4 groups

// proj role: 64 nodes/block, 16 nodes/wave (FMA-bound)
#define NODES_BLK 64
#define NBLK_PROJ 1563                        // ceil(100000/64)
#define SMEM_BYTES 52224                      // proj role: (2*64*68 + 64*68) * 4

#define LOG2E 1.44269504f

// Packed-f16 DPP rotate-add: reduces BOTH halves (two edges) at once.
template<int CTRL>
__device__ __forceinline__ __half2 hror_add(__half2 t) {
    int x = __builtin_amdgcn_mov_dpp(__builtin_bit_cast(int, t), CTRL, 0xF, 0xF, true);
    return __hadd2(t, __builtin_bit_cast(__half2, x));
}
__device__ __forceinline__ __half2 head_reduce_h2(__half2 t) {
    t = hror_add<0x121>(t);
    t = hror_add<0x122>(t);
    t = hror_add<0x124>(t);
    t = hror_add<0x128>(t);
    return t;
}

// ---------------- Fused kernel 1: proj (blocks 0..1562) + bucketa (1563..1953).
// proj first: bucketa's 391 latency-bound blocks trail into the drain and
// overlap proj compute (r18's bucketa-first ordering starved the CUs).
__global__ __launch_bounds__(256) void proj_bucketa_kernel(
        const float* __restrict__ x,
        const float* __restrict__ Ws, const float* __restrict__ bs,
        const float* __restrict__ Wr, const float* __restrict__ br,
        const int* __restrict__ senders, const int* __restrict__ receivers,
        unsigned short* __restrict__ sph, unsigned short* __restrict__ rph,
        int* __restrict__ bktcnt, int* __restrict__ bkt) {
    __shared__ __align__(16) char smem[SMEM_BYTES];
    int tid = threadIdx.x;
    if (blockIdx.x < NBLK_PROJ) {
        // ---- proj role: LDS-staged register-blocked GEMM, 16 nodes/wave.
        float* wsT = (float*)smem;            // [64*68]
        float* wrT = wsT + 64 * 68;           // [64*68]
        float* xsh = wrT + 64 * 68;           // [64*68]
        for (int i = tid; i < 4096; i += 256) {
            int k = i >> 6, o = i & 63;
            wsT[o * 68 + k] = Ws[i];
            wrT[o * 68 + k] = Wr[i];
        }
        int nb = blockIdx.x * NODES_BLK;
        for (int i = 0; i < 4; ++i) {
            int g = i * 256 + tid;
            int nl = g >> 4;
            int k4 = g & 15;
            if (nb + nl < N_NODES) {
                float4 v = ((const float4*)(x + ((size_t)(nb + nl) << 6)))[k4];
                *(float4*)(xsh + nl * 68 + (k4 << 2)) = v;
            }
        }
        __syncthreads();
        int o = tid & 63;
        int w = tid >> 6;
        float bsv = bs[o], brv = br[o];
        float accs[16], accr[16];
#pragma unroll
        for (int p = 0; p < 16; ++p) { accs[p] = bsv; accr[p] = brv; }
        const float4* ws4 = (const float4*)wsT + o * 17;
        const float4* wr4 = (const float4*)wrT + o * 17;
        const float4* xs4 = (const float4*)xsh + (w << 4) * 17;
#pragma unroll 4
        for (int k4 = 0; k4 < 16; ++k4) {
            float4 a = ws4[k4];
            float4 b = wr4[k4];
#pragma unroll
            for (int p = 0; p < 16; ++p) {
                float4 xv = xs4[p * 17 + k4];    // wave-uniform broadcast
                accs[p] += xv.x * a.x + xv.y * a.y + xv.z * a.z + xv.w * a.w;
                accr[p] += xv.x * b.x + xv.y * b.y + xv.z * b.z + xv.w * b.w;
            }
        }
        int node0 = nb + (w << 4);
#pragma unroll
        for (int p = 0; p < 16; ++p) {
            int node = node0 + p;
            if (node < N_NODES) {
                sph[(node << 6) + o] = __half_as_ushort(__float2half_rn(accs[p]));
                rph[(node << 6) + o] = __half_as_ushort(__float2half_rn(accr[p]));
            }
        }
    } else {
        // ---- bucketa role: LDS histogram -> one global atomic per (tile,bucket)
        // -> LDS-ranked scatter of packed ((r&255)<<17 | sender).
        int* hist = (int*)smem;               // [NBKT]
        int* base = hist + NBKT;
        int* cur  = base + NBKT;
        for (int i = tid; i < NBKT; i += 256) hist[i] = 0;
        __syncthreads();
        int g0 = (blockIdx.x - NBLK_PROJ) * (TILE / 4);
        int4 r[4], s[4];
        bool v[4];
#pragma unroll
        for (int t = 0; t < 4; ++t) {
            int g = g0 + t * 256 + tid;
            v[t] = (g < NGRP);
            if (v[t]) {
                r[t] = ((const int4*)receivers)[g];
                s[t] = ((const int4*)senders)[g];
                atomicAdd(&hist[r[t].x >> BKT_SHIFT], 1);
                atomicAdd(&hist[r[t].y >> BKT_SHIFT], 1);
                atomicAdd(&hist[r[t].z >> BKT_SHIFT], 1);
                atomicAdd(&hist[r[t].w >> BKT_SHIFT], 1);
            }
        }
        __syncthreads();
        for (int i = tid; i < NBKT; i += 256) {
            int h = hist[i];
            base[i] = (h > 0) ? atomicAdd(&bktcnt[i], h) : 0;
            cur[i] = 0;
        }
        __syncthreads();
#pragma unroll
        for (int t = 0; t < 4; ++t) {
            if (v[t]) {
                int b, rk, slot;
                b = r[t].x >> BKT_SHIFT; rk = atomicAdd(&cur[b], 1); slot = base[b] + rk;
                if (slot < BKT_CAP) bkt[b * BKT_CAP + slot] = ((r[t].x & (BKT_NODES - 1)) << 17) | s[t].x;
                b = r[t].y >> BKT_SHIFT; rk = atomicAdd(&cur[b], 1); slot = base[b] + rk;
                if (slot < BKT_CAP) bkt[b * BKT_CAP + slot] = ((r[t].y & (BKT_NODES - 1)) << 17) | s[t].y;
                b = r[t].z >> BKT_SHIFT; rk = atomicAdd(&cur[b], 1); slot = base[b] + rk;
                if (slot < BKT_CAP) bkt[b * BKT_CAP + slot] = ((r[t].z & (BKT_NODES - 1)) << 17) | s[t].z;
                b = r[t].w >> BKT_SHIFT; rk = atomicAdd(&cur[b], 1); slot = base[b] + rk;
                if (slot < BKT_CAP) bkt[b * BKT_CAP + slot] = ((r[t].w & (BKT_NODES - 1)) << 17) | s[t].w;
            }
        }
    }
}

// ---------------- Phase B: per-bucket CSR fill with LDS cursors.
// 391 blocks x 1024 threads. csr[r*64+slot] = sender*128 (byte offset);
// cursor[] (true degree) written at the end -> no cursor memset.
__global__ __launch_bounds__(1024) void bucketb_kernel(
        const int* __restrict__ bktcnt, const int* __restrict__ bkt,
        int* __restrict__ cursor, int* __restrict__ csr) {
    __shared__ int lcur[BKT_NODES];
    int tid = threadIdx.x;
    int b = blockIdx.x;
    if (tid < BKT_NODES) lcur[tid] = 0;
    __syncthreads();
    int cnt = bktcnt[b];
    if (cnt > BKT_CAP) cnt = BKT_CAP;
    const int* bb = bkt + b * BKT_CAP;
    for (int i = tid; i < cnt; i += 1024) {
        int vv = bb[i];
        int rl = vv >> 17;
        int sv = vv & 0x1FFFF;
        int slot = atomicAdd(&lcur[rl], 1);
        if (slot < SLOTS) csr[((((b << BKT_SHIFT) + rl)) << 6) + slot] = sv << 7;
    }
    __syncthreads();
    if (tid < BKT_NODES) {
        int node = (b << BKT_SHIFT) + tid;
        if (node < N_NODES) cursor[node] = lcur[tid];
    }
}

// ---------------- Fused per-node: logits + softmax + weighted gather.
// One wave per node; lane = output element (h*16+d). UNIFORM MASKED BATCHES:
// every batch runs the same packed-f16 path; the last batch selects safe
// offsets via wave-uniform scalar select and zeroes invalid p halves with one
// v_and (p=0 => zero contribution). No f32 tail path, no divergent epilogue.
// Ping-pong A/B buffers (named arrays only) avoid per-batch register copies.
__global__ __launch_bounds__(256) void fused_gather_kernel(
                                    const unsigned short* __restrict__ sph,
                                    const unsigned short* __restrict__ rph,
                                    const int* __restrict__ csr,
                                    const int* __restrict__ cursor,
                                    const float* __restrict__ aw,
                                    const float* __restrict__ ab,
                                    float* __restrict__ out) {
    int wave = (blockIdx.x * blockDim.x + threadIdx.x) >> 6;   // grid covers exactly N_NODES
    wave = __builtin_amdgcn_readfirstlane(wave);               // provably wave-uniform
    int lane = threadIdx.x & 63;
    int deg = cursor[wave];                   // scalar load
    deg = (deg > SLOTS) ? SLOTS : deg;
    const int* cbase = csr + (wave << 6);     // uniform base -> s_load rows
    const char* splb = (const char*)sph + (lane << 1);   // csr holds byte offsets
    float rp  = __half2float(__ushort_as_half(rph[(wave << 6) + lane]));
    float awc = aw[lane & 15];
    __half2 k_pk   = __float2half2_rn(LOG2E);
    __half2 rpk_pk = __float2half2_rn(rp * LOG2E);
    __half2 aw2_pk = __float2half2_rn(awc * LOG2E);          // exp2-domain aw
    __half2 rpa_pk = __float2half2_rn(rp * awc * LOG2E);
    __half2 ones   = __float2half2_rn(1.0f);
    __half2 neg2   = __float2half2_rn(-2.0f);
    __half2 l2a   = __float2half2_rn(0.0f), l2b   = __float2half2_rn(0.0f);
    __half2 acc2a = __float2half2_rn(0.0f), acc2b = __float2half2_rn(0.0f);

    float res = 0.f;
    if (deg > 0) {
        int nbt = (deg + 7) >> 3;             // number of 8-edge batches (last masked)
        int off0 = cbase[0];                  // safe fallback offset (deg>0)
        unsigned short bufA[8], bufB[8];

        // Load batch m into dst; mask offsets only if m is the last batch.
#define LOADB(dst, m)                                                          \
        {                                                                      \
            int i0m = (m) << 3;                                                \
            bool lastm = ((m) == nbt - 1);                                     \
            _Pragma("unroll")                                                  \
            for (int j = 0; j < 8; ++j) {                                      \
                int idx = i0m + j;                                             \
                int off = cbase[idx];          /* idx<64: in padded row */     \
                if (lastm) off = (idx < deg) ? off : off0;  /* scalar sel */   \
                dst[j] = *(const unsigned short*)(splb + off);                 \
            }                                                                  \
        }

#define COMPUTE(buf, kk)                                                       \
        {                                                                      \
            bool last = ((kk) == nbt - 1);                                     \
            int i0c = (kk) << 3;                                               \
            _Pragma("unroll")                                                  \
            for (int j = 0; j < 4; ++j) {                                      \
                __half2 sp  = __halves2half2(__ushort_as_half(buf[2 * j]),     \
                                             __ushort_as_half(buf[2 * j + 1]));\
                __half2 w   = h2exp2(__hfma2(sp, k_pk, rpk_pk));               \
                __half2 u   = __hadd2(w, ones);                                \
                __half2 den = __hfma2(u, u, ones);                             \
                __half2 r   = h2rcp(den);                                      \
                __half2 f   = __hfma2(neg2, r, ones);                          \
                __half2 za  = __hfma2(sp, aw2_pk, rpa_pk);                     \
                __half2 tt  = head_reduce_h2(__hmul2(za, f));                  \
                __half2 p   = h2exp2(tt);                                      \
                if (last) {                                                    \
                    unsigned m = ((i0c + 2 * j)     < deg ? 0x0000FFFFu : 0u)  \
                               | ((i0c + 2 * j + 1) < deg ? 0xFFFF0000u : 0u); \
                    p = __builtin_bit_cast(__half2,                            \
                            (unsigned)(__builtin_bit_cast(unsigned, p) & m));  \
                }                                                              \
                if (j & 1) { l2b = __hadd2(l2b, p); acc2b = __hfma2(p, sp, acc2b); } \
                else       { l2a = __hadd2(l2a, p); acc2a = __hfma2(p, sp, acc2a); } \
            }                                                                  \
        }

        LOADB(bufA, 0);
        int k = 0;
        while (true) {
            if (k + 1 < nbt) LOADB(bufB, k + 1);
            COMPUTE(bufA, k);
            ++k; if (k >= nbt) break;
            if (k + 1 < nbt) LOADB(bufA, k + 1);
            COMPUTE(bufB, k);
            ++k; if (k >= nbt) break;
        }
#undef LOADB
#undef COMPUTE
        __half2 l2   = __hadd2(l2a, l2b);
        __half2 acc2 = __hadd2(acc2a, acc2b);
        float l   = __low2float(l2) + __high2float(l2);
        float acc = __low2float(acc2) + __high2float(acc2);
        res = acc * __builtin_amdgcn_rcpf(l);
    }
    out[(wave << 6) + lane] = res;
}

extern "C" void kernel_launch(void* const* d_in, const int* in_sizes, int n_in,
                              void* d_out, int out_size, void* d_ws, size_t ws_size,
                              hipStream_t stream) {
    const float* x  = (const float*)d_in[0];
    const float* Ws = (const float*)d_in[1];
    const float* bs = (const float*)d_in[2];
    const float* Wr = (const float*)d_in[3];
    const float* br = (const float*)d_in[4];
    const float* aw = (const float*)d_in[5];
    const float* ab = (const float*)d_in[6];
    const int* senders   = (const int*)d_in[7];
    const int* receivers = (const int*)d_in[8];
    float* out = (float*)d_out;

    // Workspace layout (~60 MB):
    char* wsp = (char*)d_ws;
    unsigned short* sph = (unsigned short*)wsp;  wsp += (size_t)N_NODES * EMBED * 2;  // 12.8 MB
    unsigned short* rph = (unsigned short*)wsp;  wsp += (size_t)N_NODES * EMBED * 2;  // 12.8 MB
    int* csr    = (int*)wsp;  wsp += (size_t)N_NODES * SLOTS * 4;    // 25.6 MB
    int* cursor = (int*)wsp;  wsp += (size_t)N_NODES * 4;            // 0.4 MB
    int* bkt    = (int*)wsp;  wsp += (size_t)NBKT * BKT_CAP * 4;     // 8.0 MB
    int* bktcnt = (int*)wsp;  wsp += 512 * 4;

    hipMemsetAsync(bktcnt, 0, NBKT * 4, stream);

    proj_bucketa_kernel<<<NBLK_PROJ + NTILE, 256, 0, stream>>>(
        x, Ws, bs, Wr, br, senders, receivers, sph, rph, bktcnt, bkt);

    bucketb_kernel<<<NBKT, 1024, 0, stream>>>(bktcnt, bkt, cursor, csr);

    int gather_blocks = (N_NODES * 64 + 255) / 256;
    fused_gather_kernel<<<gather_blocks, 256, 0, stream>>>(sph, rph, csr, cursor,
                                                           aw, ab, out);
}

// Round 22
// 127.598 us; speedup vs baseline: 1.0518x; 1.0518x over previous
//
#include <hip/hip_runtime.h>
#include <hip/hip_fp16.h>
#include <math.h>

#define N_NODES 100000
#define N_EDGES 1600000
#define EMBED 64
#define HEADS 4
#define HDIM 16

// Padded CSR: 64 slots per node (degree is Poisson(16); max over 100K nodes < 50)
#define SLOTS 64

// Two-phase bucket partition (no global returning atomics on the hot path):
#define BKT_SHIFT 8
#define BKT_NODES 256                         // receivers per bucket
#define NBKT 391                              // ceil(100000/256)
#define BKT_CAP 5120                          // mean 4096 + 16 sigma
#define TILE 4096                             // edges per bucketa-role block
#define NTILE 391                             // ceil(1600000/4096)
#define NGRP (N_EDGES / 4)                    // 400000 int4 groups

// proj role: 64 nodes/block, 16 nodes/wave (FMA-bound)
#define NODES_BLK 64
#define NBLK_PROJ 1563                        // ceil(100000/64)
#define SMEM_BYTES 52224                      // proj role: (2*64*68 + 64*68) * 4

#define LOG2E 1.44269504f

typedef __attribute__((ext_vector_type(4))) unsigned int uint32x4;

// Scalar-tail mish (f32): tanh(softplus(z)) = 1 - 2/((1+e^z)^2 + 1); mish(z)*awc.
__device__ __forceinline__ float mish_aw(float z, float awc) {
    float ex  = __expf(fminf(z, 30.f));
    float u   = 1.f + ex;
    float den = fmaf(u, u, 1.f);
    float f   = fmaf(-2.f, __builtin_amdgcn_rcpf(den), 1.f);
    return z * awc * f;
}

// f32 DPP rotate-add: sum-reduce + broadcast across each 16-lane head group.
template<int CTRL>
__device__ __forceinline__ float ror_add(float t) {
    int x = __builtin_amdgcn_mov_dpp(__float_as_int(t), CTRL, 0xF, 0xF, true);
    return t + __int_as_float(x);
}
__device__ __forceinline__ float head_reduce(float t) {
    t = ror_add<0x121>(t);
    t = ror_add<0x122>(t);
    t = ror_add<0x124>(t);
    t = ror_add<0x128>(t);
    return t;
}

// Packed-f16 DPP rotate-add: reduces BOTH halves (two edges) at once.
template<int CTRL>
__device__ __forceinline__ __half2 hror_add(__half2 t) {
    int x = __builtin_amdgcn_mov_dpp(__builtin_bit_cast(int, t), CTRL, 0xF, 0xF, true);
    return __hadd2(t, __builtin_bit_cast(__half2, x));
}
__device__ __forceinline__ __half2 head_reduce_h2(__half2 t) {
    t = hror_add<0x121>(t);
    t = hror_add<0x122>(t);
    t = hror_add<0x124>(t);
    t = hror_add<0x128>(t);
    return t;
}

// ---------------- Fused kernel 1: proj (blocks 0..1562) + bucketa (1563..1953).
// proj first: bucketa's 391 latency-bound blocks trail into the drain and
// overlap proj compute (r18's bucketa-first ordering starved the CUs).
__global__ __launch_bounds__(256) void proj_bucketa_kernel(
        const float* __restrict__ x,
        const float* __restrict__ Ws, const float* __restrict__ bs,
        const float* __restrict__ Wr, const float* __restrict__ br,
        const int* __restrict__ senders, const int* __restrict__ receivers,
        unsigned short* __restrict__ sph, unsigned short* __restrict__ rph,
        int* __restrict__ bktcnt, int* __restrict__ bkt) {
    __shared__ __align__(16) char smem[SMEM_BYTES];
    int tid = threadIdx.x;
    if (blockIdx.x < NBLK_PROJ) {
        // ---- proj role: LDS-staged register-blocked GEMM, 16 nodes/wave.
        float* wsT = (float*)smem;            // [64*68]
        float* wrT = wsT + 64 * 68;           // [64*68]
        float* xsh = wrT + 64 * 68;           // [64*68]
        for (int i = tid; i < 4096; i += 256) {
            int k = i >> 6, o = i & 63;
            wsT[o * 68 + k] = Ws[i];
            wrT[o * 68 + k] = Wr[i];
        }
        int nb = blockIdx.x * NODES_BLK;
        for (int i = 0; i < 4; ++i) {
            int g = i * 256 + tid;
            int nl = g >> 4;
            int k4 = g & 15;
            if (nb + nl < N_NODES) {
                float4 v = ((const float4*)(x + ((size_t)(nb + nl) << 6)))[k4];
                *(float4*)(xsh + nl * 68 + (k4 << 2)) = v;
            }
        }
        __syncthreads();
        int o = tid & 63;
        int w = tid >> 6;
        float bsv = bs[o], brv = br[o];
        float accs[16], accr[16];
#pragma unroll
        for (int p = 0; p < 16; ++p) { accs[p] = bsv; accr[p] = brv; }
        const float4* ws4 = (const float4*)wsT + o * 17;
        const float4* wr4 = (const float4*)wrT + o * 17;
        const float4* xs4 = (const float4*)xsh + (w << 4) * 17;
#pragma unroll 4
        for (int k4 = 0; k4 < 16; ++k4) {
            float4 a = ws4[k4];
            float4 b = wr4[k4];
#pragma unroll
            for (int p = 0; p < 16; ++p) {
                float4 xv = xs4[p * 17 + k4];    // wave-uniform broadcast
                accs[p] += xv.x * a.x + xv.y * a.y + xv.z * a.z + xv.w * a.w;
                accr[p] += xv.x * b.x + xv.y * b.y + xv.z * b.z + xv.w * b.w;
            }
        }
        int node0 = nb + (w << 4);
#pragma unroll
        for (int p = 0; p < 16; ++p) {
            int node = node0 + p;
            if (node < N_NODES) {
                sph[(node << 6) + o] = __half_as_ushort(__float2half_rn(accs[p]));
                rph[(node << 6) + o] = __half_as_ushort(__float2half_rn(accr[p]));
            }
        }
    } else {
        // ---- bucketa role: LDS histogram -> one global atomic per (tile,bucket)
        // -> LDS-ranked scatter of packed ((r&255)<<17 | sender).
        int* hist = (int*)smem;               // [NBKT]
        int* base = hist + NBKT;
        int* cur  = base + NBKT;
        for (int i = tid; i < NBKT; i += 256) hist[i] = 0;
        __syncthreads();
        int g0 = (blockIdx.x - NBLK_PROJ) * (TILE / 4);
        int4 r[4], s[4];
        bool v[4];
#pragma unroll
        for (int t = 0; t < 4; ++t) {
            int g = g0 + t * 256 + tid;
            v[t] = (g < NGRP);
            if (v[t]) {
                r[t] = ((const int4*)receivers)[g];
                s[t] = ((const int4*)senders)[g];
                atomicAdd(&hist[r[t].x >> BKT_SHIFT], 1);
                atomicAdd(&hist[r[t].y >> BKT_SHIFT], 1);
                atomicAdd(&hist[r[t].z >> BKT_SHIFT], 1);
                atomicAdd(&hist[r[t].w >> BKT_SHIFT], 1);
            }
        }
        __syncthreads();
        for (int i = tid; i < NBKT; i += 256) {
            int h = hist[i];
            base[i] = (h > 0) ? atomicAdd(&bktcnt[i], h) : 0;
            cur[i] = 0;
        }
        __syncthreads();
#pragma unroll
        for (int t = 0; t < 4; ++t) {
            if (v[t]) {
                int b, rk, slot;
                b = r[t].x >> BKT_SHIFT; rk = atomicAdd(&cur[b], 1); slot = base[b] + rk;
                if (slot < BKT_CAP) bkt[b * BKT_CAP + slot] = ((r[t].x & (BKT_NODES - 1)) << 17) | s[t].x;
                b = r[t].y >> BKT_SHIFT; rk = atomicAdd(&cur[b], 1); slot = base[b] + rk;
                if (slot < BKT_CAP) bkt[b * BKT_CAP + slot] = ((r[t].y & (BKT_NODES - 1)) << 17) | s[t].y;
                b = r[t].z >> BKT_SHIFT; rk = atomicAdd(&cur[b], 1); slot = base[b] + rk;
                if (slot < BKT_CAP) bkt[b * BKT_CAP + slot] = ((r[t].z & (BKT_NODES - 1)) << 17) | s[t].z;
                b = r[t].w >> BKT_SHIFT; rk = atomicAdd(&cur[b], 1); slot = base[b] + rk;
                if (slot < BKT_CAP) bkt[b * BKT_CAP + slot] = ((r[t].w & (BKT_NODES - 1)) << 17) | s[t].w;
            }
        }
    }
}

// ---------------- Phase B: per-bucket CSR fill with LDS cursors.
// 391 blocks x 1024 threads. csr[r*64+slot] = sender*128 (byte offset);
// cursor[] (true degree) written at the end -> no cursor memset.
__global__ __launch_bounds__(1024) void bucketb_kernel(
        const int* __restrict__ bktcnt, const int* __restrict__ bkt,
        int* __restrict__ cursor, int* __restrict__ csr) {
    __shared__ int lcur[BKT_NODES];
    int tid = threadIdx.x;
    int b = blockIdx.x;
    if (tid < BKT_NODES) lcur[tid] = 0;
    __syncthreads();
    int cnt = bktcnt[b];
    if (cnt > BKT_CAP) cnt = BKT_CAP;
    const int* bb = bkt + b * BKT_CAP;
    for (int i = tid; i < cnt; i += 1024) {
        int vv = bb[i];
        int rl = vv >> 17;
        int sv = vv & 0x1FFFF;
        int slot = atomicAdd(&lcur[rl], 1);
        if (slot < SLOTS) csr[((((b << BKT_SHIFT) + rl)) << 6) + slot] = sv << 7;
    }
    __syncthreads();
    if (tid < BKT_NODES) {
        int node = (b << BKT_SHIFT) + tid;
        if (node < N_NODES) cursor[node] = lcur[tid];
    }
}

// ---------------- Fused per-node: logits + softmax + weighted gather.
// One wave per node; lane = output element (h*16+d). r19 structure. Scattered
// loads via buffer_load_ushort (scalar row offset in soffset, lane<<1 in
// voffset: zero per-load VALU address math). CRITICAL: the s_waitcnt asm
// threads the loaded registers through "+v" operands, creating a true data
// dependency so the compiler cannot schedule consumers before the wait
// (r21's NaN was exactly that hoist).
__global__ __launch_bounds__(256) void fused_gather_kernel(
                                    const unsigned short* __restrict__ sph,
                                    const unsigned short* __restrict__ rph,
                                    const int* __restrict__ csr,
                                    const int* __restrict__ cursor,
                                    const float* __restrict__ aw,
                                    const float* __restrict__ ab,
                                    float* __restrict__ out) {
    int wave = (blockIdx.x * blockDim.x + threadIdx.x) >> 6;   // grid covers exactly N_NODES
    wave = __builtin_amdgcn_readfirstlane(wave);               // provably wave-uniform
    int lane = threadIdx.x & 63;
    int deg = cursor[wave];                   // scalar load
    deg = (deg > SLOTS) ? SLOTS : deg;
    const int* cbase = csr + (wave << 6);     // uniform base -> s_load rows
    float rp  = __half2float(__ushort_as_half(rph[(wave << 6) + lane]));
    float awc = aw[lane & 15];

    // SRSRC for sph: raw buffer, bounds check disabled.
    unsigned long long sb = (unsigned long long)(const void*)sph;
    uint32x4 rsrc;
    rsrc.x = (unsigned)sb;
    rsrc.y = (unsigned)(sb >> 32);            // stride=0
    rsrc.z = 0xFFFFFFFFu;                     // num_records: disable check
    rsrc.w = 0x00020000u;                     // raw untyped
    int voff = lane << 1;                     // loop-invariant lane byte offset

#define BLOAD(dstv, soff)                                                      \
    asm volatile("buffer_load_ushort %0, %1, %2, %3 offen"                     \
                 : "=v"(dstv) : "v"(voff), "s"(rsrc), "s"(soff))

    __half2 k_pk   = __float2half2_rn(LOG2E);
    __half2 rpk_pk = __float2half2_rn(rp * LOG2E);
    __half2 aw2_pk = __float2half2_rn(awc * LOG2E);          // exp2-domain aw
    __half2 rpa_pk = __float2half2_rn(rp * awc * LOG2E);
    __half2 ones   = __float2half2_rn(1.0f);
    __half2 neg2   = __float2half2_rn(-2.0f);
    __half2 l2a   = __float2half2_rn(0.0f), l2b   = __float2half2_rn(0.0f);
    __half2 acc2a = __float2half2_rn(0.0f), acc2b = __float2half2_rn(0.0f);
    float l_t = 0.f, acc_t = 0.f;             // f32 scalar-tail accumulators
    int nb8 = deg >> 3;
    for (int k = 0; k < nb8; ++k) {
        const int* cb = cbase + (k << 3);
        unsigned su[8];
#pragma unroll
        for (int j = 0; j < 8; ++j) BLOAD(su[j], cb[j]);
        // Dependency-threaded wait: consumers of su[] now depend on THIS asm.
        asm volatile("s_waitcnt vmcnt(0)"
                     : "+v"(su[0]), "+v"(su[1]), "+v"(su[2]), "+v"(su[3]),
                       "+v"(su[4]), "+v"(su[5]), "+v"(su[6]), "+v"(su[7]));
#pragma unroll
        for (int j = 0; j < 4; ++j) {
            __half2 sp  = __halves2half2(__ushort_as_half((unsigned short)su[2 * j]),
                                         __ushort_as_half((unsigned short)su[2 * j + 1]));
            __half2 w   = h2exp2(__hfma2(sp, k_pk, rpk_pk));   // e^(sp+rp); inf ok
            __half2 u   = __hadd2(w, ones);
            __half2 den = __hfma2(u, u, ones);
            __half2 r   = h2rcp(den);
            __half2 f   = __hfma2(neg2, r, ones);
            __half2 za  = __hfma2(sp, aw2_pk, rpa_pk);         // (sp+rp)*aw*log2e
            __half2 tt  = head_reduce_h2(__hmul2(za, f));      // logit*log2e
            __half2 p   = h2exp2(tt);
            if (j & 1) { l2b = __hadd2(l2b, p); acc2b = __hfma2(p, sp, acc2b); }
            else       { l2a = __hadd2(l2a, p); acc2a = __hfma2(p, sp, acc2a); }
        }
    }
    int i = nb8 << 3;
    for (; i + 2 <= deg; i += 2) {
        unsigned s0, s1;
        BLOAD(s0, cbase[i]);
        BLOAD(s1, cbase[i + 1]);
        asm volatile("s_waitcnt vmcnt(0)" : "+v"(s0), "+v"(s1));
        __half2 sp  = __halves2half2(__ushort_as_half((unsigned short)s0),
                                     __ushort_as_half((unsigned short)s1));
        __half2 w   = h2exp2(__hfma2(sp, k_pk, rpk_pk));
        __half2 u   = __hadd2(w, ones);
        __half2 den = __hfma2(u, u, ones);
        __half2 r   = h2rcp(den);
        __half2 f   = __hfma2(neg2, r, ones);
        __half2 za  = __hfma2(sp, aw2_pk, rpa_pk);
        __half2 tt  = head_reduce_h2(__hmul2(za, f));
        __half2 p   = h2exp2(tt);
        l2a   = __hadd2(l2a, p);
        acc2a = __hfma2(p, sp, acc2a);
    }
    if (i < deg) {
        unsigned s0;
        BLOAD(s0, cbase[i]);
        asm volatile("s_waitcnt vmcnt(0)" : "+v"(s0));
        float sp0 = __half2float(__ushort_as_half((unsigned short)s0));
        float t0 = head_reduce(mish_aw(sp0 + rp, awc));
        float p = __builtin_amdgcn_exp2f(t0 * LOG2E);
        l_t += p;
        acc_t = fmaf(p, sp0, acc_t);
    }
#undef BLOAD
    __half2 l2   = __hadd2(l2a, l2b);
    __half2 acc2 = __hadd2(acc2a, acc2b);
    float l   = __low2float(l2) + __high2float(l2) + l_t;
    float acc = __low2float(acc2) + __high2float(acc2) + acc_t;
    out[(wave << 6) + lane] = (deg > 0) ? acc * __builtin_amdgcn_rcpf(l) : 0.f;
}

extern "C" void kernel_launch(void* const* d_in, const int* in_sizes, int n_in,
                              void* d_out, int out_size, void* d_ws, size_t ws_size,
                              hipStream_t stream) {
    const float* x  = (const float*)d_in[0];
    const float* Ws = (const float*)d_in[1];
    const float* bs = (const float*)d_in[2];
    const float* Wr = (const float*)d_in[3];
    const float* br = (const float*)d_in[4];
    const float* aw = (const float*)d_in[5];
    const float* ab = (const float*)d_in[6];
    const int* senders   = (const int*)d_in[7];
    const int* receivers = (const int*)d_in[8];
    float* out = (float*)d_out;

    // Workspace layout (~60 MB):
    char* wsp = (char*)d_ws;
    unsigned short* sph = (unsigned short*)wsp;  wsp += (size_t)N_NODES * EMBED * 2;  // 12.8 MB
    unsigned short* rph = (unsigned short*)wsp;  wsp += (size_t)N_NODES * EMBED * 2;  // 12.8 MB
    int* csr    = (int*)wsp;  wsp += (size_t)N_NODES * SLOTS * 4;    // 25.6 MB
    int* cursor = (int*)wsp;  wsp += (size_t)N_NODES * 4;            // 0.4 MB
    int* bkt    = (int*)wsp;  wsp += (size_t)NBKT * BKT_CAP * 4;     // 8.0 MB
    int* bktcnt = (int*)wsp;  wsp += 512 * 4;

    hipMemsetAsync(bktcnt, 0, NBKT * 4, stream);

    proj_bucketa_kernel<<<NBLK_PROJ + NTILE, 256, 0, stream>>>(
        x, Ws, bs, Wr, br, senders, receivers, sph, rph, bktcnt, bkt);

    bucketb_kernel<<<NBKT, 1024, 0, stream>>>(bktcnt, bkt, cursor, csr);

    int gather_blocks = (N_NODES * 64 + 255) / 256;
    fused_gather_kernel<<<gather_blocks, 256, 0, stream>>>(sph, rph, csr, cursor,
                                                           aw, ab, out);
}

// Round 24
// 125.241 us; speedup vs baseline: 1.0715x; 1.0188x over previous
//
#include <hip/hip_runtime.h>
#include <hip/hip_fp16.h>
#include <math.h>

#define N_NODES 100000
#define N_EDGES 1600000
#define EMBED 64
#define HEADS 4
#define HDIM 16

// Padded CSR: 64 slots per node (degree is Poisson(16); max over 100K nodes < 50)
#define SLOTS 64

// Two-phase bucket partition (no global returning atomics on the hot path):
#define BKT_SHIFT 8
#define BKT_NODES 256                         // receivers per bucket
#define NBKT 391                              // ceil(100000/256)
#define BKT_CAP 5120                          // mean 4096 + 16 sigma
#define TILE 4096                             // edges per bucketa-role block
#define NTILE 391                             // ceil(1600000/4096)
#define NGRP (N_EDGES / 4)                    // 400000 int4 groups

// proj role: 64 nodes/block, 16 nodes/wave (FMA-bound)
#define NODES_BLK 64
#define NBLK_PROJ 1563                        // ceil(100000/64)
#define SMEM_BYTES 52224                      // proj role: (2*64*68 + 64*68) * 4

#define LOG2E 1.44269504f

// Scalar-tail mish (f32): tanh(softplus(z)) = 1 - 2/((1+e^z)^2 + 1); mish(z)*awc.
__device__ __forceinline__ float mish_aw(float z, float awc) {
    float ex  = __expf(fminf(z, 30.f));
    float u   = 1.f + ex;
    float den = fmaf(u, u, 1.f);
    float f   = fmaf(-2.f, __builtin_amdgcn_rcpf(den), 1.f);
    return z * awc * f;
}

// f32 DPP rotate-add: sum-reduce + broadcast across each 16-lane head group.
template<int CTRL>
__device__ __forceinline__ float ror_add(float t) {
    int x = __builtin_amdgcn_mov_dpp(__float_as_int(t), CTRL, 0xF, 0xF, true);
    return t + __int_as_float(x);
}
__device__ __forceinline__ float head_reduce(float t) {
    t = ror_add<0x121>(t);
    t = ror_add<0x122>(t);
    t = ror_add<0x124>(t);
    t = ror_add<0x128>(t);
    return t;
}

// Packed-f16 DPP rotate-add: reduces BOTH halves (two edges) at once.
template<int CTRL>
__device__ __forceinline__ __half2 hror_add(__half2 t) {
    int x = __builtin_amdgcn_mov_dpp(__builtin_bit_cast(int, t), CTRL, 0xF, 0xF, true);
    return __hadd2(t, __builtin_bit_cast(__half2, x));
}
__device__ __forceinline__ __half2 head_reduce_h2(__half2 t) {
    t = hror_add<0x121>(t);
    t = hror_add<0x122>(t);
    t = hror_add<0x124>(t);
    t = hror_add<0x128>(t);
    return t;
}

// ---------------- Fused kernel 1: proj (blocks 0..1562) + bucketa (1563..1953).
// proj first: bucketa's 391 latency-bound blocks trail into the drain and
// overlap proj compute (r18's bucketa-first ordering starved the CUs).
__global__ __launch_bounds__(256) void proj_bucketa_kernel(
        const float* __restrict__ x,
        const float* __restrict__ Ws, const float* __restrict__ bs,
        const float* __restrict__ Wr, const float* __restrict__ br,
        const int* __restrict__ senders, const int* __restrict__ receivers,
        unsigned short* __restrict__ sph, unsigned short* __restrict__ rph,
        int* __restrict__ bktcnt, int* __restrict__ bkt) {
    __shared__ __align__(16) char smem[SMEM_BYTES];
    int tid = threadIdx.x;
    if (blockIdx.x < NBLK_PROJ) {
        // ---- proj role: LDS-staged register-blocked GEMM, 16 nodes/wave.
        float* wsT = (float*)smem;            // [64*68]
        float* wrT = wsT + 64 * 68;           // [64*68]
        float* xsh = wrT + 64 * 68;           // [64*68]
        for (int i = tid; i < 4096; i += 256) {
            int k = i >> 6, o = i & 63;
            wsT[o * 68 + k] = Ws[i];
            wrT[o * 68 + k] = Wr[i];
        }
        int nb = blockIdx.x * NODES_BLK;
        for (int i = 0; i < 4; ++i) {
            int g = i * 256 + tid;
            int nl = g >> 4;
            int k4 = g & 15;
            if (nb + nl < N_NODES) {
                float4 v = ((const float4*)(x + ((size_t)(nb + nl) << 6)))[k4];
                *(float4*)(xsh + nl * 68 + (k4 << 2)) = v;
            }
        }
        __syncthreads();
        int o = tid & 63;
        int w = tid >> 6;
        float bsv = bs[o], brv = br[o];
        float accs[16], accr[16];
#pragma unroll
        for (int p = 0; p < 16; ++p) { accs[p] = bsv; accr[p] = brv; }
        const float4* ws4 = (const float4*)wsT + o * 17;
        const float4* wr4 = (const float4*)wrT + o * 17;
        const float4* xs4 = (const float4*)xsh + (w << 4) * 17;
#pragma unroll 4
        for (int k4 = 0; k4 < 16; ++k4) {
            float4 a = ws4[k4];
            float4 b = wr4[k4];
#pragma unroll
            for (int p = 0; p < 16; ++p) {
                float4 xv = xs4[p * 17 + k4];    // wave-uniform broadcast
                accs[p] += xv.x * a.x + xv.y * a.y + xv.z * a.z + xv.w * a.w;
                accr[p] += xv.x * b.x + xv.y * b.y + xv.z * b.z + xv.w * b.w;
            }
        }
        int node0 = nb + (w << 4);
#pragma unroll
        for (int p = 0; p < 16; ++p) {
            int node = node0 + p;
            if (node < N_NODES) {
                sph[(node << 6) + o] = __half_as_ushort(__float2half_rn(accs[p]));
                rph[(node << 6) + o] = __half_as_ushort(__float2half_rn(accr[p]));
            }
        }
    } else {
        // ---- bucketa role: LDS histogram -> one global atomic per (tile,bucket)
        // -> LDS-ranked scatter of packed ((r&255)<<17 | sender).
        int* hist = (int*)smem;               // [NBKT]
        int* base = hist + NBKT;
        int* cur  = base + NBKT;
        for (int i = tid; i < NBKT; i += 256) hist[i] = 0;
        __syncthreads();
        int g0 = (blockIdx.x - NBLK_PROJ) * (TILE / 4);
        int4 r[4], s[4];
        bool v[4];
#pragma unroll
        for (int t = 0; t < 4; ++t) {
            int g = g0 + t * 256 + tid;
            v[t] = (g < NGRP);
            if (v[t]) {
                r[t] = ((const int4*)receivers)[g];
                s[t] = ((const int4*)senders)[g];
                atomicAdd(&hist[r[t].x >> BKT_SHIFT], 1);
                atomicAdd(&hist[r[t].y >> BKT_SHIFT], 1);
                atomicAdd(&hist[r[t].z >> BKT_SHIFT], 1);
                atomicAdd(&hist[r[t].w >> BKT_SHIFT], 1);
            }
        }
        __syncthreads();
        for (int i = tid; i < NBKT; i += 256) {
            int h = hist[i];
            base[i] = (h > 0) ? atomicAdd(&bktcnt[i], h) : 0;
            cur[i] = 0;
        }
        __syncthreads();
#pragma unroll
        for (int t = 0; t < 4; ++t) {
            if (v[t]) {
                int b, rk, slot;
                b = r[t].x >> BKT_SHIFT; rk = atomicAdd(&cur[b], 1); slot = base[b] + rk;
                if (slot < BKT_CAP) bkt[b * BKT_CAP + slot] = ((r[t].x & (BKT_NODES - 1)) << 17) | s[t].x;
                b = r[t].y >> BKT_SHIFT; rk = atomicAdd(&cur[b], 1); slot = base[b] + rk;
                if (slot < BKT_CAP) bkt[b * BKT_CAP + slot] = ((r[t].y & (BKT_NODES - 1)) << 17) | s[t].y;
                b = r[t].z >> BKT_SHIFT; rk = atomicAdd(&cur[b], 1); slot = base[b] + rk;
                if (slot < BKT_CAP) bkt[b * BKT_CAP + slot] = ((r[t].z & (BKT_NODES - 1)) << 17) | s[t].z;
                b = r[t].w >> BKT_SHIFT; rk = atomicAdd(&cur[b], 1); slot = base[b] + rk;
                if (slot < BKT_CAP) bkt[b * BKT_CAP + slot] = ((r[t].w & (BKT_NODES - 1)) << 17) | s[t].w;
            }
        }
    }
}

// ---------------- Phase B: per-bucket CSR fill with LDS cursors.
// 391 blocks x 1024 threads. csr[r*64+slot] = sender*128 (byte offset);
// cursor[] (true degree) written at the end -> no cursor memset.
__global__ __launch_bounds__(1024) void bucketb_kernel(
        const int* __restrict__ bktcnt, const int* __restrict__ bkt,
        int* __restrict__ cursor, int* __restrict__ csr) {
    __shared__ int lcur[BKT_NODES];
    int tid = threadIdx.x;
    int b = blockIdx.x;
    if (tid < BKT_NODES) lcur[tid] = 0;
    __syncthreads();
    int cnt = bktcnt[b];
    if (cnt > BKT_CAP) cnt = BKT_CAP;
    const int* bb = bkt + b * BKT_CAP;
    for (int i = tid; i < cnt; i += 1024) {
        int vv = bb[i];
        int rl = vv >> 17;
        int sv = vv & 0x1FFFF;
        int slot = atomicAdd(&lcur[rl], 1);
        if (slot < SLOTS) csr[((((b << BKT_SHIFT) + rl)) << 6) + slot] = sv << 7;
    }
    __syncthreads();
    if (tid < BKT_NODES) {
        int node = (b << BKT_SHIFT) + tid;
        if (node < N_NODES) cursor[node] = lcur[tid];
    }
}

// ---------------- Fused per-node: logits + softmax + weighted gather.
// One wave per node; lane = output element (h*16+d).
// VALU-slimmed: ab dropped (softmax shift-invariant), LOG2E folded into the
// aw/rp*aw constants (logit lands in exp2 domain), w=e^(sp+rp) via single
// packed exp2 (f16 overflow is the benign mish=z saturation path), and the
// final exp + l/acc accumulation fully packed f16 (|logit| <~ 8 stat. bound,
// p <= e^8 ~ 3000 << f16 max). Pure HIP — compiler-scheduled loads (r22/r23
// showed asm buffer_load + waitcnt variants are neutral or racey).
__global__ __launch_bounds__(256) void fused_gather_kernel(
                                    const unsigned short* __restrict__ sph,
                                    const unsigned short* __restrict__ rph,
                                    const int* __restrict__ csr,
                                    const int* __restrict__ cursor,
                                    const float* __restrict__ aw,
                                    const float* __restrict__ ab,
                                    float* __restrict__ out) {
    int wave = (blockIdx.x * blockDim.x + threadIdx.x) >> 6;   // grid covers exactly N_NODES
    wave = __builtin_amdgcn_readfirstlane(wave);               // provably wave-uniform
    int lane = threadIdx.x & 63;
    int deg = cursor[wave];                   // scalar load
    deg = (deg > SLOTS) ? SLOTS : deg;
    const int* cbase = csr + (wave << 6);     // uniform base -> s_load rows
    const char* splb = (const char*)sph + (lane << 1);   // csr holds byte offsets
    float rp  = __half2float(__ushort_as_half(rph[(wave << 6) + lane]));
    float awc = aw[lane & 15];
    __half2 k_pk   = __float2half2_rn(LOG2E);
    __half2 rpk_pk = __float2half2_rn(rp * LOG2E);
    __half2 aw2_pk = __float2half2_rn(awc * LOG2E);          // exp2-domain aw
    __half2 rpa_pk = __float2half2_rn(rp * awc * LOG2E);
    __half2 ones   = __float2half2_rn(1.0f);
    __half2 neg2   = __float2half2_rn(-2.0f);
    __half2 l2a   = __float2half2_rn(0.0f), l2b   = __float2half2_rn(0.0f);
    __half2 acc2a = __float2half2_rn(0.0f), acc2b = __float2half2_rn(0.0f);
    float l_t = 0.f, acc_t = 0.f;             // f32 scalar-tail accumulators
    int nb8 = deg >> 3;
    unsigned short cur[8], nxt[8];
    if (nb8 > 0) {
#pragma unroll
        for (int j = 0; j < 8; ++j) cur[j] = *(const unsigned short*)(splb + cbase[j]);
    }
    for (int k = 0; k < nb8; ++k) {
        if (k + 1 < nb8) {
            const int* cb = cbase + ((k + 1) << 3);
#pragma unroll
            for (int j = 0; j < 8; ++j) nxt[j] = *(const unsigned short*)(splb + cb[j]);
        }
#pragma unroll
        for (int j = 0; j < 4; ++j) {
            __half2 sp  = __halves2half2(__ushort_as_half(cur[2 * j]),
                                         __ushort_as_half(cur[2 * j + 1]));
            __half2 w   = h2exp2(__hfma2(sp, k_pk, rpk_pk));   // e^(sp+rp); inf ok
            __half2 u   = __hadd2(w, ones);
            __half2 den = __hfma2(u, u, ones);
            __half2 r   = h2rcp(den);
            __half2 f   = __hfma2(neg2, r, ones);
            __half2 za  = __hfma2(sp, aw2_pk, rpa_pk);         // (sp+rp)*aw*log2e
            __half2 tt  = head_reduce_h2(__hmul2(za, f));      // logit*log2e
            __half2 p   = h2exp2(tt);
            if (j & 1) { l2b = __hadd2(l2b, p); acc2b = __hfma2(p, sp, acc2b); }
            else       { l2a = __hadd2(l2a, p); acc2a = __hfma2(p, sp, acc2a); }
        }
#pragma unroll
        for (int j = 0; j < 8; ++j) cur[j] = nxt[j];
    }
    int i = nb8 << 3;
    for (; i + 2 <= deg; i += 2) {
        __half2 sp  = __halves2half2(__ushort_as_half(*(const unsigned short*)(splb + cbase[i])),
                                     __ushort_as_half(*(const unsigned short*)(splb + cbase[i + 1])));
        __half2 w   = h2exp2(__hfma2(sp, k_pk, rpk_pk));
        __half2 u   = __hadd2(w, ones);
        __half2 den = __hfma2(u, u, ones);
        __half2 r   = h2rcp(den);
        __half2 f   = __hfma2(neg2, r, ones);
        __half2 za  = __hfma2(sp, aw2_pk, rpa_pk);
        __half2 tt  = head_reduce_h2(__hmul2(za, f));
        __half2 p   = h2exp2(tt);
        l2a   = __hadd2(l2a, p);
        acc2a = __hfma2(p, sp, acc2a);
    }
    if (i < deg) {
        float sp0 = __half2float(__ushort_as_half(*(const unsigned short*)(splb + cbase[i])));
        float t0 = head_reduce(mish_aw(sp0 + rp, awc));
        float p = __builtin_amdgcn_exp2f(t0 * LOG2E);
        l_t += p;
        acc_t = fmaf(p, sp0, acc_t);
    }
    __half2 l2   = __hadd2(l2a, l2b);
    __half2 acc2 = __hadd2(acc2a, acc2b);
    float l   = __low2float(l2) + __high2float(l2) + l_t;
    float acc = __low2float(acc2) + __high2float(acc2) + acc_t;
    out[(wave << 6) + lane] = (deg > 0) ? acc * __builtin_amdgcn_rcpf(l) : 0.f;
}

extern "C" void kernel_launch(void* const* d_in, const int* in_sizes, int n_in,
                              void* d_out, int out_size, void* d_ws, size_t ws_size,
                              hipStream_t stream) {
    const float* x  = (const float*)d_in[0];
    const float* Ws = (const float*)d_in[1];
    const float* bs = (const float*)d_in[2];
    const float* Wr = (const float*)d_in[3];
    const float* br = (const float*)d_in[4];
    const float* aw = (const float*)d_in[5];
    const float* ab = (const float*)d_in[6];
    const int* senders   = (const int*)d_in[7];
    const int* receivers = (const int*)d_in[8];
    float* out = (float*)d_out;

    // Workspace layout (~60 MB):
    char* wsp = (char*)d_ws;
    unsigned short* sph = (unsigned short*)wsp;  wsp += (size_t)N_NODES * EMBED * 2;  // 12.8 MB
    unsigned short* rph = (unsigned short*)wsp;  wsp += (size_t)N_NODES * EMBED * 2;  // 12.8 MB
    int* csr    = (int*)wsp;  wsp += (size_t)N_NODES * SLOTS * 4;    // 25.6 MB
    int* cursor = (int*)wsp;  wsp += (size_t)N_NODES * 4;            // 0.4 MB
    int* bkt    = (int*)wsp;  wsp += (size_t)NBKT * BKT_CAP * 4;     // 8.0 MB
    int* bktcnt = (int*)wsp;  wsp += 512 * 4;

    hipMemsetAsync(bktcnt, 0, NBKT * 4, stream);

    proj_bucketa_kernel<<<NBLK_PROJ + NTILE, 256, 0, stream>>>(
        x, Ws, bs, Wr, br, senders, receivers, sph, rph, bktcnt, bkt);

    bucketb_kernel<<<NBKT, 1024, 0, stream>>>(bktcnt, bkt, cursor, csr);

    int gather_blocks = (N_NODES * 64 + 255) / 256;
    fused_gather_kernel<<<gather_blocks, 256, 0, stream>>>(sph, rph, csr, cursor,
                                                           aw, ab, out);
}

// Round 25
// 118.831 us; speedup vs baseline: 1.1294x; 1.0539x over previous
//
#include <hip/hip_runtime.h>
#include <hip/hip_fp16.h>
#include <math.h>

#define N_NODES 100000
#define N_EDGES 1600000
#define EMBED 64
#define HEADS 4
#define HDIM 16

// Padded CSR: 64 slots per node (degree is Poisson(16); max over 100K nodes < 50)
#define SLOTS 64

// Fixed-slot bucket partition: NO global atomics, NO memset.
// Each (tile,bucket) owns a fixed 32-slot segment of bkt; rank via LDS cursor.
// P(Poisson(10.47) > 32) ~ 1e-8 x 153K cells -> overflow never happens (and a
// drop is graceful). cnt2 is fully overwritten every call -> deterministic.
#define BKT_SHIFT 8
#define BKT_NODES 256                         // receivers per bucket
#define NBKT 391                              // ceil(100000/256)
#define CAP2 32                               // slots per (tile,bucket) segment
#define TILE 4096                             // edges per bucketa-role block
#define NTILE 391                             // ceil(1600000/4096)
#define NGRP (N_EDGES / 4)                    // 400000 int4 groups

// proj role: 64 nodes/block, 16 nodes/wave (FMA-bound)
#define NODES_BLK 64
#define NBLK_PROJ 1563                        // ceil(100000/64)
#define SMEM_BYTES 52224                      // proj role: (2*64*68 + 64*68) * 4

#define LOG2E 1.44269504f

// Scalar-tail mish (f32): tanh(softplus(z)) = 1 - 2/((1+e^z)^2 + 1); mish(z)*awc.
__device__ __forceinline__ float mish_aw(float z, float awc) {
    float ex  = __expf(fminf(z, 30.f));
    float u   = 1.f + ex;
    float den = fmaf(u, u, 1.f);
    float f   = fmaf(-2.f, __builtin_amdgcn_rcpf(den), 1.f);
    return z * awc * f;
}

// f32 DPP rotate-add: sum-reduce + broadcast across each 16-lane head group.
template<int CTRL>
__device__ __forceinline__ float ror_add(float t) {
    int x = __builtin_amdgcn_mov_dpp(__float_as_int(t), CTRL, 0xF, 0xF, true);
    return t + __int_as_float(x);
}
__device__ __forceinline__ float head_reduce(float t) {
    t = ror_add<0x121>(t);
    t = ror_add<0x122>(t);
    t = ror_add<0x124>(t);
    t = ror_add<0x128>(t);
    return t;
}

// Packed-f16 DPP rotate-add: reduces BOTH halves (two edges) at once.
template<int CTRL>
__device__ __forceinline__ __half2 hror_add(__half2 t) {
    int x = __builtin_amdgcn_mov_dpp(__builtin_bit_cast(int, t), CTRL, 0xF, 0xF, true);
    return __hadd2(t, __builtin_bit_cast(__half2, x));
}
__device__ __forceinline__ __half2 head_reduce_h2(__half2 t) {
    t = hror_add<0x121>(t);
    t = hror_add<0x122>(t);
    t = hror_add<0x124>(t);
    t = hror_add<0x128>(t);
    return t;
}

// ---------------- Fused kernel 1: proj (blocks 0..1562) + bucketa (1563..1953).
// proj first: bucketa's 391 latency-bound blocks trail into the drain and
// overlap proj compute. bucketa role is single-pass: LDS-rank -> fixed-slot
// write, per-(tile,bucket) counts stored non-atomically to cnt2.
__global__ __launch_bounds__(256) void proj_bucketa_kernel(
        const float* __restrict__ x,
        const float* __restrict__ Ws, const float* __restrict__ bs,
        const float* __restrict__ Wr, const float* __restrict__ br,
        const int* __restrict__ senders, const int* __restrict__ receivers,
        unsigned short* __restrict__ sph, unsigned short* __restrict__ rph,
        int* __restrict__ cnt2, int* __restrict__ bkt) {
    __shared__ __align__(16) char smem[SMEM_BYTES];
    int tid = threadIdx.x;
    if (blockIdx.x < NBLK_PROJ) {
        // ---- proj role: LDS-staged register-blocked GEMM, 16 nodes/wave.
        float* wsT = (float*)smem;            // [64*68]
        float* wrT = wsT + 64 * 68;           // [64*68]
        float* xsh = wrT + 64 * 68;           // [64*68]
        for (int i = tid; i < 4096; i += 256) {
            int k = i >> 6, o = i & 63;
            wsT[o * 68 + k] = Ws[i];
            wrT[o * 68 + k] = Wr[i];
        }
        int nb = blockIdx.x * NODES_BLK;
        for (int i = 0; i < 4; ++i) {
            int g = i * 256 + tid;
            int nl = g >> 4;
            int k4 = g & 15;
            if (nb + nl < N_NODES) {
                float4 v = ((const float4*)(x + ((size_t)(nb + nl) << 6)))[k4];
                *(float4*)(xsh + nl * 68 + (k4 << 2)) = v;
            }
        }
        __syncthreads();
        int o = tid & 63;
        int w = tid >> 6;
        float bsv = bs[o], brv = br[o];
        float accs[16], accr[16];
#pragma unroll
        for (int p = 0; p < 16; ++p) { accs[p] = bsv; accr[p] = brv; }
        const float4* ws4 = (const float4*)wsT + o * 17;
        const float4* wr4 = (const float4*)wrT + o * 17;
        const float4* xs4 = (const float4*)xsh + (w << 4) * 17;
#pragma unroll 4
        for (int k4 = 0; k4 < 16; ++k4) {
            float4 a = ws4[k4];
            float4 b = wr4[k4];
#pragma unroll
            for (int p = 0; p < 16; ++p) {
                float4 xv = xs4[p * 17 + k4];    // wave-uniform broadcast
                accs[p] += xv.x * a.x + xv.y * a.y + xv.z * a.z + xv.w * a.w;
                accr[p] += xv.x * b.x + xv.y * b.y + xv.z * b.z + xv.w * b.w;
            }
        }
        int node0 = nb + (w << 4);
#pragma unroll
        for (int p = 0; p < 16; ++p) {
            int node = node0 + p;
            if (node < N_NODES) {
                sph[(node << 6) + o] = __half_as_ushort(__float2half_rn(accs[p]));
                rph[(node << 6) + o] = __half_as_ushort(__float2half_rn(accr[p]));
            }
        }
    } else {
        // ---- bucketa role: single-pass LDS-rank -> fixed-slot scatter of
        // packed ((r&255)<<17 | sender). No histogram, no global atomics.
        int* cur = (int*)smem;                // [NBKT]
        for (int i = tid; i < NBKT; i += 256) cur[i] = 0;
        __syncthreads();
        int tile = blockIdx.x - NBLK_PROJ;
        int g0 = tile * (TILE / 4);
#pragma unroll
        for (int t = 0; t < 4; ++t) {
            int g = g0 + t * 256 + tid;
            if (g < NGRP) {
                int4 r = ((const int4*)receivers)[g];
                int4 s = ((const int4*)senders)[g];
                int b, rk;
                b = r.x >> BKT_SHIFT; rk = atomicAdd(&cur[b], 1);
                if (rk < CAP2) bkt[(b * NTILE + tile) * CAP2 + rk] = ((r.x & (BKT_NODES - 1)) << 17) | s.x;
                b = r.y >> BKT_SHIFT; rk = atomicAdd(&cur[b], 1);
                if (rk < CAP2) bkt[(b * NTILE + tile) * CAP2 + rk] = ((r.y & (BKT_NODES - 1)) << 17) | s.y;
                b = r.z >> BKT_SHIFT; rk = atomicAdd(&cur[b], 1);
                if (rk < CAP2) bkt[(b * NTILE + tile) * CAP2 + rk] = ((r.z & (BKT_NODES - 1)) << 17) | s.z;
                b = r.w >> BKT_SHIFT; rk = atomicAdd(&cur[b], 1);
                if (rk < CAP2) bkt[(b * NTILE + tile) * CAP2 + rk] = ((r.w & (BKT_NODES - 1)) << 17) | s.w;
            }
        }
        __syncthreads();
        for (int i = tid; i < NBKT; i += 256) {
            int c = cur[i];
            cnt2[i * NTILE + tile] = (c > CAP2) ? CAP2 : c;   // plain store, no memset needed
        }
    }
}

// ---------------- Phase B: per-bucket CSR fill from fixed-slot segments.
// 391 blocks x 1024 threads walk the 391x32 slot space (13 iterations),
// count-guarded so invalid slots touch no memory. LDS cursors; cursor[]
// (true degree) written at the end.
__global__ __launch_bounds__(1024) void bucketb_kernel(
        const int* __restrict__ cnt2, const int* __restrict__ bkt,
        int* __restrict__ cursor, int* __restrict__ csr) {
    __shared__ int scnt[NTILE];               // per-segment counts for this bucket
    __shared__ int lcur[BKT_NODES];
    int tid = threadIdx.x;
    int b = blockIdx.x;
    if (tid < NTILE) scnt[tid] = cnt2[b * NTILE + tid];
    if (tid < BKT_NODES) lcur[tid] = 0;
    __syncthreads();
    const int* bb = bkt + (size_t)b * NTILE * CAP2;
    for (int i = tid; i < NTILE * CAP2; i += 1024) {
        int seg = i >> 5;                     // CAP2 = 32
        int sl  = i & (CAP2 - 1);
        if (sl < scnt[seg]) {
            int vv = bb[i];
            int rl = vv >> 17;
            int sv = vv & 0x1FFFF;
            int slot = atomicAdd(&lcur[rl], 1);
            if (slot < SLOTS) csr[((((b << BKT_SHIFT) + rl)) << 6) + slot] = sv << 7;
        }
    }
    __syncthreads();
    if (tid < BKT_NODES) {
        int node = (b << BKT_SHIFT) + tid;
        if (node < N_NODES) cursor[node] = lcur[tid];
    }
}

// ---------------- Fused per-node: logits + softmax + weighted gather.
// One wave per node; lane = output element (h*16+d). Verified r19/r24 version:
// packed-f16 pipeline, exp2-domain constants, ab dropped (shift-invariant),
// compiler-scheduled loads.
__global__ __launch_bounds__(256) void fused_gather_kernel(
                                    const unsigned short* __restrict__ sph,
                                    const unsigned short* __restrict__ rph,
                                    const int* __restrict__ csr,
                                    const int* __restrict__ cursor,
                                    const float* __restrict__ aw,
                                    const float* __restrict__ ab,
                                    float* __restrict__ out) {
    int wave = (blockIdx.x * blockDim.x + threadIdx.x) >> 6;   // grid covers exactly N_NODES
    wave = __builtin_amdgcn_readfirstlane(wave);               // provably wave-uniform
    int lane = threadIdx.x & 63;
    int deg = cursor[wave];                   // scalar load
    deg = (deg > SLOTS) ? SLOTS : deg;
    const int* cbase = csr + (wave << 6);     // uniform base -> s_load rows
    const char* splb = (const char*)sph + (lane << 1);   // csr holds byte offsets
    float rp  = __half2float(__ushort_as_half(rph[(wave << 6) + lane]));
    float awc = aw[lane & 15];
    __half2 k_pk   = __float2half2_rn(LOG2E);
    __half2 rpk_pk = __float2half2_rn(rp * LOG2E);
    __half2 aw2_pk = __float2half2_rn(awc * LOG2E);          // exp2-domain aw
    __half2 rpa_pk = __float2half2_rn(rp * awc * LOG2E);
    __half2 ones   = __float2half2_rn(1.0f);
    __half2 neg2   = __float2half2_rn(-2.0f);
    __half2 l2a   = __float2half2_rn(0.0f), l2b   = __float2half2_rn(0.0f);
    __half2 acc2a = __float2half2_rn(0.0f), acc2b = __float2half2_rn(0.0f);
    float l_t = 0.f, acc_t = 0.f;             // f32 scalar-tail accumulators
    int nb8 = deg >> 3;
    unsigned short cur[8], nxt[8];
    if (nb8 > 0) {
#pragma unroll
        for (int j = 0; j < 8; ++j) cur[j] = *(const unsigned short*)(splb + cbase[j]);
    }
    for (int k = 0; k < nb8; ++k) {
        if (k + 1 < nb8) {
            const int* cb = cbase + ((k + 1) << 3);
#pragma unroll
            for (int j = 0; j < 8; ++j) nxt[j] = *(const unsigned short*)(splb + cb[j]);
        }
#pragma unroll
        for (int j = 0; j < 4; ++j) {
            __half2 sp  = __halves2half2(__ushort_as_half(cur[2 * j]),
                                         __ushort_as_half(cur[2 * j + 1]));
            __half2 w   = h2exp2(__hfma2(sp, k_pk, rpk_pk));   // e^(sp+rp); inf ok
            __half2 u   = __hadd2(w, ones);
            __half2 den = __hfma2(u, u, ones);
            __half2 r   = h2rcp(den);
            __half2 f   = __hfma2(neg2, r, ones);
            __half2 za  = __hfma2(sp, aw2_pk, rpa_pk);         // (sp+rp)*aw*log2e
            __half2 tt  = head_reduce_h2(__hmul2(za, f));      // logit*log2e
            __half2 p   = h2exp2(tt);
            if (j & 1) { l2b = __hadd2(l2b, p); acc2b = __hfma2(p, sp, acc2b); }
            else       { l2a = __hadd2(l2a, p); acc2a = __hfma2(p, sp, acc2a); }
        }
#pragma unroll
        for (int j = 0; j < 8; ++j) cur[j] = nxt[j];
    }
    int i = nb8 << 3;
    for (; i + 2 <= deg; i += 2) {
        __half2 sp  = __halves2half2(__ushort_as_half(*(const unsigned short*)(splb + cbase[i])),
                                     __ushort_as_half(*(const unsigned short*)(splb + cbase[i + 1])));
        __half2 w   = h2exp2(__hfma2(sp, k_pk, rpk_pk));
        __half2 u   = __hadd2(w, ones);
        __half2 den = __hfma2(u, u, ones);
        __half2 r   = h2rcp(den);
        __half2 f   = __hfma2(neg2, r, ones);
        __half2 za  = __hfma2(sp, aw2_pk, rpa_pk);
        __half2 tt  = head_reduce_h2(__hmul2(za, f));
        __half2 p   = h2exp2(tt);
        l2a   = __hadd2(l2a, p);
        acc2a = __hfma2(p, sp, acc2a);
    }
    if (i < deg) {
        float sp0 = __half2float(__ushort_as_half(*(const unsigned short*)(splb + cbase[i])));
        float t0 = head_reduce(mish_aw(sp0 + rp, awc));
        float p = __builtin_amdgcn_exp2f(t0 * LOG2E);
        l_t += p;
        acc_t = fmaf(p, sp0, acc_t);
    }
    __half2 l2   = __hadd2(l2a, l2b);
    __half2 acc2 = __hadd2(acc2a, acc2b);
    float l   = __low2float(l2) + __high2float(l2) + l_t;
    float acc = __low2float(acc2) + __high2float(acc2) + acc_t;
    out[(wave << 6) + lane] = (deg > 0) ? acc * __builtin_amdgcn_rcpf(l) : 0.f;
}

extern "C" void kernel_launch(void* const* d_in, const int* in_sizes, int n_in,
                              void* d_out, int out_size, void* d_ws, size_t ws_size,
                              hipStream_t stream) {
    const float* x  = (const float*)d_in[0];
    const float* Ws = (const float*)d_in[1];
    const float* bs = (const float*)d_in[2];
    const float* Wr = (const float*)d_in[3];
    const float* br = (const float*)d_in[4];
    const float* aw = (const float*)d_in[5];
    const float* ab = (const float*)d_in[6];
    const int* senders   = (const int*)d_in[7];
    const int* receivers = (const int*)d_in[8];
    float* out = (float*)d_out;

    // Workspace layout (~71.8 MB):
    char* wsp = (char*)d_ws;
    unsigned short* sph = (unsigned short*)wsp;  wsp += (size_t)N_NODES * EMBED * 2;  // 12.8 MB
    unsigned short* rph = (unsigned short*)wsp;  wsp += (size_t)N_NODES * EMBED * 2;  // 12.8 MB
    int* csr    = (int*)wsp;  wsp += (size_t)N_NODES * SLOTS * 4;          // 25.6 MB
    int* cursor = (int*)wsp;  wsp += (size_t)N_NODES * 4;                  // 0.4 MB
    int* bkt    = (int*)wsp;  wsp += (size_t)NBKT * NTILE * CAP2 * 4;      // 19.6 MB
    int* cnt2   = (int*)wsp;  wsp += (size_t)NBKT * NTILE * 4;             // 0.6 MB

    // No memset: cnt2 is fully overwritten by bucketa every call.
    proj_bucketa_kernel<<<NBLK_PROJ + NTILE, 256, 0, stream>>>(
        x, Ws, bs, Wr, br, senders, receivers, sph, rph, cnt2, bkt);

    bucketb_kernel<<<NBKT, 1024, 0, stream>>>(cnt2, bkt, cursor, csr);

    int gather_blocks = (N_NODES * 64 + 255) / 256;
    fused_gather_kernel<<<gather_blocks, 256, 0, stream>>>(sph, rph, csr, cursor,
                                                           aw, ab, out);
}